// Round 2
// baseline (352.374 us; speedup 1.0000x reference)
//
#include <hip/hip_runtime.h>
#include <hip/hip_bf16.h>
#include <stdint.h>

// EfficientAttentionBlock: 8x8 non-overlapping window attention.
// B=4, C=256, H=W=256 -> 4096 windows of [C=256, P=64].
// One 256-thread block (4 waves) per window. bf16 MFMA, fp32 accumulate.

#define CIN    256
#define CQK    32
#define HIMG   256
#define WIMG   256
#define CH_STRIDE 65536   // H*W

typedef __bf16 bf16x8 __attribute__((ext_vector_type(8)));
typedef float  f32x4  __attribute__((ext_vector_type(4)));

// LDS layout (bytes). Vt overlays Xt+Qt region after they are dead.
#define XT_OFF 0        // Xt[64 px][256 ch] bf16, swizzled 16B blocks: 32768 B
#define QT_OFF 32768    // Qt[64 px][40 ch pad] bf16: 5120 B
#define KT_OFF 37888    // Kt[64 px][40 ch pad] bf16: 5120 B
#define AT_OFF 43008    // At[64 p][72 q pad] bf16: 9216 B
#define VT_OFF 0        // Vt[256 c][72 q pad] bf16: 36864 B (overlay)
#define LDS_BYTES 52224

__device__ __forceinline__ int swz8(int p) { return (p ^ (p >> 3)) & 7; }

__device__ __forceinline__ bf16x8 cvt8(float4 a, float4 b) {
  bf16x8 r;
  r[0] = (__bf16)a.x; r[1] = (__bf16)a.y; r[2] = (__bf16)a.z; r[3] = (__bf16)a.w;
  r[4] = (__bf16)b.x; r[5] = (__bf16)b.y; r[6] = (__bf16)b.z; r[7] = (__bf16)b.w;
  return r;
}

__device__ __forceinline__ uint32_t pack2(float lo, float hi) {
  union { __bf16 h[2]; uint32_t u; } un;
  un.h[0] = (__bf16)lo; un.h[1] = (__bf16)hi;
  return un.u;
}

__global__ __launch_bounds__(256, 3) void win_attn_kernel(
    const float* __restrict__ x,  const float* __restrict__ wq,
    const float* __restrict__ bq, const float* __restrict__ wk,
    const float* __restrict__ bk, const float* __restrict__ wv,
    const float* __restrict__ bv, const float* __restrict__ gamma,
    float* __restrict__ out, int nwin)
{
  __shared__ __attribute__((aligned(16))) unsigned char lds[LDS_BYTES];

  // XCD-aware swizzle: 8 XCDs get contiguous chunks so adjacent ww windows
  // (sharing 128B cache lines) land on the same XCD L2. nwin % 8 == 0.
  int bid   = blockIdx.x;
  int chunk = nwin >> 3;
  int swz   = (bid & 7) * chunk + (bid >> 3);
  int b  = swz >> 10;          // 1024 windows per batch image (32x32)
  int hw = (swz >> 5) & 31;
  int ww = swz & 31;
  size_t win_off = (size_t)b * (CIN * CH_STRIDE) + (size_t)hw * 8 * WIMG + (size_t)ww * 8;
  const float* xw = x + win_off;
  float* ow = out + win_off;

  int t = threadIdx.x;

  // ---------------- Phase 0: global x -> Xt (bf16, swizzled) ----------------
  // task id = c2*16 + i*2 + half : channel-pair c2 (0..127), window row i, row half.
  #pragma unroll
  for (int it = 0; it < 8; ++it) {
    int id   = it * 256 + t;
    int half = id & 1;
    int i    = (id >> 1) & 7;
    int c2   = id >> 4;
    const float* r0 = xw + (size_t)(2 * c2) * CH_STRIDE + i * WIMG + half * 4;
    float4 va = *(const float4*)r0;
    float4 vb = *(const float4*)(r0 + CH_STRIDE);
    float ax[4] = {va.x, va.y, va.z, va.w};
    float bx[4] = {vb.x, vb.y, vb.z, vb.w};
    int blk = c2 >> 2;
    int sub = (c2 & 3) * 4;
    #pragma unroll
    for (int jj = 0; jj < 4; ++jj) {
      int p = i * 8 + half * 4 + jj;
      *(uint32_t*)(lds + XT_OFF + p * 512 + ((blk ^ swz8(p)) << 4) + sub) =
          pack2(ax[jj], bx[jj]);
    }
  }
  __syncthreads();

  int w = t >> 6, l = t & 63, l16 = l & 15, lq = l >> 4;

  // ---------------- Phase 1: Q/K/V projections (shared K-loop) --------------
  // wave w: Q (w=0,1) or K (w=2,3) rows (w&1)*16..+16 ; V rows w*64..+64.
  f32x4 vacc[4][4] = {};
  f32x4 qacc[4]    = {};
  const float* wqk = (w < 2) ? wq : wk;
  int qkrow = (w & 1) * 16;

  #pragma unroll
  for (int ks = 0; ks < 8; ++ks) {
    bf16x8 xb[4];
    #pragma unroll
    for (int qi = 0; qi < 4; ++qi) {
      int p = qi * 16 + l16;
      xb[qi] = *(const bf16x8*)(lds + XT_OFF + p * 512 +
                                (((ks * 4 + lq) ^ swz8(p)) << 4));
    }
    {
      const float* ap = wqk + (qkrow + l16) * CIN + ks * 32 + lq * 8;
      bf16x8 af = cvt8(*(const float4*)ap, *(const float4*)(ap + 4));
      #pragma unroll
      for (int qi = 0; qi < 4; ++qi)
        qacc[qi] = __builtin_amdgcn_mfma_f32_16x16x32_bf16(af, xb[qi], qacc[qi], 0, 0, 0);
    }
    #pragma unroll
    for (int ci = 0; ci < 4; ++ci) {
      const float* ap = wv + (w * 64 + ci * 16 + l16) * CIN + ks * 32 + lq * 8;
      bf16x8 af = cvt8(*(const float4*)ap, *(const float4*)(ap + 4));
      #pragma unroll
      for (int qi = 0; qi < 4; ++qi)
        vacc[ci][qi] = __builtin_amdgcn_mfma_f32_16x16x32_bf16(af, xb[qi], vacc[ci][qi], 0, 0, 0);
    }
  }

  // store Q/K (+bias) as [pixel][channel] bf16 (pad stride 40)
  {
    const float* bias = (w < 2) ? bq : bk;
    int lbase = (w < 2) ? QT_OFF : KT_OFF;
    #pragma unroll
    for (int r = 0; r < 4; ++r) {
      int c = qkrow + lq * 4 + r;
      float bb = bias[c];
      #pragma unroll
      for (int qi = 0; qi < 4; ++qi) {
        int p = qi * 16 + l16;
        *(__bf16*)(lds + lbase + p * 80 + c * 2) = (__bf16)(qacc[qi][r] + bb);
      }
    }
  }
  __syncthreads();

  // ---------------- Phase 2: S = Q^T K (K=32), softmax, store At ------------
  {
    bf16x8 qa = *(const bf16x8*)(lds + QT_OFF + (w * 16 + l16) * 80 + lq * 16);
    f32x4 sacc[4];
    #pragma unroll
    for (int qi = 0; qi < 4; ++qi) {
      bf16x8 kb = *(const bf16x8*)(lds + KT_OFF + (qi * 16 + l16) * 80 + lq * 16);
      f32x4 z = {0.f, 0.f, 0.f, 0.f};
      sacc[qi] = __builtin_amdgcn_mfma_f32_16x16x32_bf16(qa, kb, z, 0, 0, 0);
    }
    #pragma unroll
    for (int r = 0; r < 4; ++r) {
      float v0 = sacc[0][r] * 0.125f, v1 = sacc[1][r] * 0.125f;
      float v2 = sacc[2][r] * 0.125f, v3 = sacc[3][r] * 0.125f;
      float m = fmaxf(fmaxf(v0, v1), fmaxf(v2, v3));
      m = fmaxf(m, __shfl_xor(m, 1)); m = fmaxf(m, __shfl_xor(m, 2));
      m = fmaxf(m, __shfl_xor(m, 4)); m = fmaxf(m, __shfl_xor(m, 8));
      float e0 = __expf(v0 - m), e1 = __expf(v1 - m);
      float e2 = __expf(v2 - m), e3 = __expf(v3 - m);
      float s = e0 + e1 + e2 + e3;
      s += __shfl_xor(s, 1); s += __shfl_xor(s, 2);
      s += __shfl_xor(s, 4); s += __shfl_xor(s, 8);
      float inv = 1.0f / s;
      int p = w * 16 + lq * 4 + r;
      *(__bf16*)(lds + AT_OFF + p * 144 + (0 + l16) * 2)  = (__bf16)(e0 * inv);
      *(__bf16*)(lds + AT_OFF + p * 144 + (16 + l16) * 2) = (__bf16)(e1 * inv);
      *(__bf16*)(lds + AT_OFF + p * 144 + (32 + l16) * 2) = (__bf16)(e2 * inv);
      *(__bf16*)(lds + AT_OFF + p * 144 + (48 + l16) * 2) = (__bf16)(e3 * inv);
    }
  }
  __syncthreads();   // all Xt/Qt/Kt reads done; At complete

  // ---------------- Phase 3: V (+bv) -> Vt (overlays Xt/Qt) -----------------
  #pragma unroll
  for (int ci = 0; ci < 4; ++ci) {
    #pragma unroll
    for (int r = 0; r < 4; ++r) {
      int c = w * 64 + ci * 16 + lq * 4 + r;
      float bb = bv[c];
      #pragma unroll
      for (int qi = 0; qi < 4; ++qi) {
        int q = qi * 16 + l16;
        *(__bf16*)(lds + VT_OFF + c * 144 + q * 2) = (__bf16)(vacc[ci][qi][r] + bb);
      }
    }
  }
  __syncthreads();

  // ---------------- Phase 4: O = V * A^T ------------------------------------
  f32x4 oacc[4][4] = {};
  #pragma unroll
  for (int ks = 0; ks < 2; ++ks) {
    bf16x8 ab[4];
    #pragma unroll
    for (int pi = 0; pi < 4; ++pi)
      ab[pi] = *(const bf16x8*)(lds + AT_OFF + (pi * 16 + l16) * 144 + ks * 64 + lq * 16);
    #pragma unroll
    for (int ci = 0; ci < 4; ++ci) {
      bf16x8 vf = *(const bf16x8*)(lds + VT_OFF + (w * 64 + ci * 16 + l16) * 144 +
                                   ks * 64 + lq * 16);
      #pragma unroll
      for (int pi = 0; pi < 4; ++pi)
        oacc[ci][pi] = __builtin_amdgcn_mfma_f32_16x16x32_bf16(vf, ab[pi], oacc[ci][pi], 0, 0, 0);
    }
  }

  // ---------------- Phase 5: epilogue: out = gamma*O + x --------------------
  float g = gamma[0];
  #pragma unroll
  for (int ci = 0; ci < 4; ++ci) {
    #pragma unroll
    for (int r = 0; r < 4; ++r) {
      int c = w * 64 + ci * 16 + lq * 4 + r;
      #pragma unroll
      for (int pi = 0; pi < 4; ++pi) {
        int p = pi * 16 + l16;
        size_t off = (size_t)c * CH_STRIDE + (p >> 3) * WIMG + (p & 7);
        ow[off] = g * oacc[ci][pi][r] + xw[off];
      }
    }
  }
}

extern "C" void kernel_launch(void* const* d_in, const int* in_sizes, int n_in,
                              void* d_out, int out_size, void* d_ws, size_t ws_size,
                              hipStream_t stream) {
  const float* x     = (const float*)d_in[0];
  const float* wq    = (const float*)d_in[1];
  const float* bq    = (const float*)d_in[2];
  const float* wk    = (const float*)d_in[3];
  const float* bk    = (const float*)d_in[4];
  const float* wv    = (const float*)d_in[5];
  const float* bv    = (const float*)d_in[6];
  const float* gamma = (const float*)d_in[7];
  float* out = (float*)d_out;

  int B = in_sizes[0] / (CIN * CH_STRIDE);   // 4
  int nwin = B * 1024;                        // 32x32 windows per image
  win_attn_kernel<<<dim3(nwin), dim3(256), 0, stream>>>(
      x, wq, bq, wk, bk, wv, bv, gamma, out, nwin);
}

// Round 3
// 300.538 us; speedup vs baseline: 1.1725x; 1.1725x over previous
//
#include <hip/hip_runtime.h>
#include <hip/hip_bf16.h>
#include <stdint.h>

// EfficientAttentionBlock: 8x8 window attention. B=4, C=256, H=W=256.
// 4096 windows; one 256-thread block per window; bf16 MFMA, fp32 accum.
// ws: bf16 weights: wq[32][256]@0, wk@8192, wv[256][256]@16384 (elems).

#define CIN    256
#define WIMG   256
#define CH_STRIDE 65536   // H*W

typedef __bf16 bf16x8 __attribute__((ext_vector_type(8)));
typedef float  f32x4  __attribute__((ext_vector_type(4)));

// LDS regions (bytes), total 40960 -> exactly 4 blocks/CU (160 KiB).
// region0 [0,32768): Xt (ph0-ph3) -> Vt (ph4-ph5) -> Ochunk (epilogue)
// region1 [32768,40960): Qt+Kt (ph1-ph2) -> At (ph4-ph5)
#define XT_OFF 0
#define VT_OFF 0
#define OC_OFF 0
#define QT_OFF 32768
#define KT_OFF 36864
#define AT_OFF 32768
#define LDS_BYTES 40960

__device__ __forceinline__ int swz8(int p) { return (p ^ (p >> 3)) & 7; }

__device__ __forceinline__ uint32_t pack2(float lo, float hi) {
  union { __bf16 h[2]; uint32_t u; } un;
  un.h[0] = (__bf16)lo; un.h[1] = (__bf16)hi;
  return un.u;
}

// ---------------- weight prep: fp32 -> bf16 row-major -----------------------
__global__ __launch_bounds__(256) void wprep_kernel(
    const float* __restrict__ wq, const float* __restrict__ wk,
    const float* __restrict__ wv, __bf16* __restrict__ out)
{
  int i = blockIdx.x * 256 + threadIdx.x;   // 20480 threads x 4 elems = 81920
  int off = i * 4;
  const float* src;
  if (off < 8192)       src = wq + off;
  else if (off < 16384) src = wk + (off - 8192);
  else                  src = wv + (off - 16384);
  float4 v = *(const float4*)src;
  __bf16 h[4] = {(__bf16)v.x, (__bf16)v.y, (__bf16)v.z, (__bf16)v.w};
  *(uint2*)(out + off) = *(const uint2*)h;
}

__global__ __launch_bounds__(256, 4) void win_attn_kernel(
    const float* __restrict__ x,  const __bf16* __restrict__ wsb,
    const float* __restrict__ bq, const float* __restrict__ bk,
    const float* __restrict__ bv, const float* __restrict__ gamma,
    float* __restrict__ out, int nwin)
{
  __shared__ __attribute__((aligned(16))) unsigned char lds[LDS_BYTES];

  // XCD-aware swizzle: contiguous chunk of windows per XCD. nwin % 8 == 0.
  int bid   = blockIdx.x;
  int chunk = nwin >> 3;
  int swz   = (bid & 7) * chunk + (bid >> 3);
  int b  = swz >> 10;
  int hw = (swz >> 5) & 31;
  int ww = swz & 31;
  size_t win_off = (size_t)b * (CIN * CH_STRIDE) + (size_t)hw * 8 * WIMG + (size_t)ww * 8;
  const float* xw = x + win_off;
  float* ow = out + win_off;

  int t = threadIdx.x;
  float g = gamma[0];

  // ---------------- ph0: global x -> Xt (bf16, swizzled) --------------------
  #pragma unroll
  for (int it = 0; it < 8; ++it) {
    int id   = it * 256 + t;
    int half = id & 1;
    int i    = (id >> 1) & 7;
    int c2   = id >> 4;
    const float* r0 = xw + (size_t)(2 * c2) * CH_STRIDE + i * WIMG + half * 4;
    float4 va = *(const float4*)r0;
    float4 vb = *(const float4*)(r0 + CH_STRIDE);
    float ax[4] = {va.x, va.y, va.z, va.w};
    float bx[4] = {vb.x, vb.y, vb.z, vb.w};
    int blk = c2 >> 2;
    int sub = (c2 & 3) * 4;
    #pragma unroll
    for (int jj = 0; jj < 4; ++jj) {
      int p = i * 8 + half * 4 + jj;
      *(uint32_t*)(lds + XT_OFF + p * 512 + ((blk ^ swz8(p)) << 4) + sub) =
          pack2(ax[jj], bx[jj]);
    }
  }
  __syncthreads();

  int w = t >> 6, l = t & 63, l16 = l & 15, lq = l >> 4;

  // ---------------- ph1: Q/K projection (waves 0,1 = Q; 2,3 = K) ------------
  // wave computes 16 rows: c in [qkrow, qkrow+16)
  int qkrow = (w & 1) * 16;
  {
    f32x4 qacc[4] = {};
    const __bf16* qrow = wsb + ((w < 2) ? 0 : 8192) + (qkrow + l16) * 256 + lq * 8;
    #pragma unroll
    for (int ks = 0; ks < 8; ++ks) {
      bf16x8 xb[4];
      #pragma unroll
      for (int qi = 0; qi < 4; ++qi) {
        int p = qi * 16 + l16;
        xb[qi] = *(const bf16x8*)(lds + XT_OFF + p * 512 +
                                  (((ks * 4 + lq) ^ swz8(p)) << 4));
      }
      bf16x8 af = *(const bf16x8*)(qrow + ks * 32);
      #pragma unroll
      for (int qi = 0; qi < 4; ++qi)
        qacc[qi] = __builtin_amdgcn_mfma_f32_16x16x32_bf16(af, xb[qi], qacc[qi], 0, 0, 0);
    }
    // store Qt/Kt [64 px][32 ch] stride 64B, 16B-block XOR swizzle
    const float* bias = (w < 2) ? bq : bk;
    int lbase = (w < 2) ? QT_OFF : KT_OFF;
    #pragma unroll
    for (int r = 0; r < 4; ++r) {
      int c = qkrow + lq * 4 + r;
      float bb = bias[c];
      #pragma unroll
      for (int qi = 0; qi < 4; ++qi) {
        int p = qi * 16 + l16;
        *(__bf16*)(lds + lbase + p * 64 + (((c >> 3) ^ (p & 3)) << 4) + (c & 7) * 2) =
            (__bf16)(qacc[qi][r] + bb);
      }
    }
  }
  __syncthreads();   // A: Qt/Kt visible

  // ---------------- ph2: S = Q^T K, softmax (in-register) -------------------
  float att[4][4];   // [r][qi] normalized attention, row p = w*16+lq*4+r
  {
    int pq = w * 16 + l16;
    bf16x8 qa = *(const bf16x8*)(lds + QT_OFF + pq * 64 + ((lq ^ (pq & 3)) << 4));
    f32x4 sacc[4];
    #pragma unroll
    for (int qi = 0; qi < 4; ++qi) {
      int pk = qi * 16 + l16;
      bf16x8 kb = *(const bf16x8*)(lds + KT_OFF + pk * 64 + ((lq ^ (pk & 3)) << 4));
      f32x4 z = {0.f, 0.f, 0.f, 0.f};
      sacc[qi] = __builtin_amdgcn_mfma_f32_16x16x32_bf16(qa, kb, z, 0, 0, 0);
    }
    #pragma unroll
    for (int r = 0; r < 4; ++r) {
      float v0 = sacc[0][r] * 0.125f, v1 = sacc[1][r] * 0.125f;
      float v2 = sacc[2][r] * 0.125f, v3 = sacc[3][r] * 0.125f;
      float m = fmaxf(fmaxf(v0, v1), fmaxf(v2, v3));
      m = fmaxf(m, __shfl_xor(m, 1)); m = fmaxf(m, __shfl_xor(m, 2));
      m = fmaxf(m, __shfl_xor(m, 4)); m = fmaxf(m, __shfl_xor(m, 8));
      float e0 = __expf(v0 - m), e1 = __expf(v1 - m);
      float e2 = __expf(v2 - m), e3 = __expf(v3 - m);
      float s = e0 + e1 + e2 + e3;
      s += __shfl_xor(s, 1); s += __shfl_xor(s, 2);
      s += __shfl_xor(s, 4); s += __shfl_xor(s, 8);
      float inv = 1.0f / s;
      att[r][0] = e0 * inv; att[r][1] = e1 * inv;
      att[r][2] = e2 * inv; att[r][3] = e3 * inv;
    }
  }

  // ---------------- ph3: V projection (wave w: rows w*64..+64) --------------
  f32x4 vacc[4][4] = {};
  {
    const __bf16* vrow = wsb + 16384 + (w * 64 + l16) * 256 + lq * 8;
    #pragma unroll
    for (int ks = 0; ks < 8; ++ks) {
      bf16x8 xb[4];
      #pragma unroll
      for (int qi = 0; qi < 4; ++qi) {
        int p = qi * 16 + l16;
        xb[qi] = *(const bf16x8*)(lds + XT_OFF + p * 512 +
                                  (((ks * 4 + lq) ^ swz8(p)) << 4));
      }
      #pragma unroll
      for (int ci = 0; ci < 4; ++ci) {
        bf16x8 vf = *(const bf16x8*)(vrow + ci * 16 * 256 + ks * 32);
        #pragma unroll
        for (int qi = 0; qi < 4; ++qi)
          vacc[ci][qi] = __builtin_amdgcn_mfma_f32_16x16x32_bf16(vf, xb[qi], vacc[ci][qi], 0, 0, 0);
      }
    }
  }
  __syncthreads();   // B: Xt + Qt/Kt reads done -> safe to overlay

  // ---------------- ph4: write Vt [256c][64q] + At [64p][64q] (XOR) ---------
  {
    int qb_lo = l16 >> 3, qlo = (l16 & 7) * 2;
    #pragma unroll
    for (int ci = 0; ci < 4; ++ci) {
      #pragma unroll
      for (int r = 0; r < 4; ++r) {
        int c = w * 64 + ci * 16 + lq * 4 + r;
        float bb = bv[c];
        #pragma unroll
        for (int qi = 0; qi < 4; ++qi) {
          *(__bf16*)(lds + VT_OFF + c * 128 + (((qi * 2 + qb_lo) ^ (c & 7)) << 4) + qlo) =
              (__bf16)(vacc[ci][qi][r] + bb);
        }
      }
    }
    #pragma unroll
    for (int r = 0; r < 4; ++r) {
      int p = w * 16 + lq * 4 + r;
      #pragma unroll
      for (int qi = 0; qi < 4; ++qi) {
        *(__bf16*)(lds + AT_OFF + p * 128 + (((qi * 2 + qb_lo) ^ (p & 7)) << 4) + qlo) =
            (__bf16)att[r][qi];
      }
    }
  }
  __syncthreads();   // C: Vt/At visible

  // ---------------- ph5: O = V * A^T --------------------------------------
  f32x4 oacc[4][4] = {};
  #pragma unroll
  for (int ks = 0; ks < 2; ++ks) {
    bf16x8 ab[4];
    #pragma unroll
    for (int pi = 0; pi < 4; ++pi) {
      int p = pi * 16 + l16;
      ab[pi] = *(const bf16x8*)(lds + AT_OFF + p * 128 + (((ks * 4 + lq) ^ (p & 7)) << 4));
    }
    #pragma unroll
    for (int ci = 0; ci < 4; ++ci) {
      int c = w * 64 + ci * 16 + l16;
      bf16x8 vf = *(const bf16x8*)(lds + VT_OFF + c * 128 + (((ks * 4 + lq) ^ (c & 7)) << 4));
      #pragma unroll
      for (int pi = 0; pi < 4; ++pi)
        oacc[ci][pi] = __builtin_amdgcn_mfma_f32_16x16x32_bf16(vf, ab[pi], oacc[ci][pi], 0, 0, 0);
    }
  }

  // ---------------- epilogue: O -> LDS transpose -> float4 out --------------
  // 2 rounds of 128 channels. Ochunk[cl][p] fp32, stride 256B, 16B-block XOR.
  #pragma unroll
  for (int round = 0; round < 2; ++round) {
    __syncthreads();   // prior region0 reads done (Vt reads / round-0 reads)
    if ((w >> 1) == round) {
      #pragma unroll
      for (int ci = 0; ci < 4; ++ci) {
        #pragma unroll
        for (int r = 0; r < 4; ++r) {
          int cl = (w & 1) * 64 + ci * 16 + lq * 4 + r;
          #pragma unroll
          for (int pi = 0; pi < 4; ++pi) {
            int p = pi * 16 + l16;
            *(float*)(lds + OC_OFF + cl * 256 + ((((p >> 2) ^ (cl & 15))) << 4) +
                      (p & 3) * 4) = oacc[ci][pi][r];
          }
        }
      }
    }
    __syncthreads();   // Ochunk visible
    #pragma unroll
    for (int j = 0; j < 8; ++j) {
      int idx = j * 256 + t;
      int cl = idx >> 4, f4 = idx & 15;
      float4 o = *(const float4*)(lds + OC_OFF + cl * 256 + ((f4 ^ (cl & 15)) << 4));
      int c = round * 128 + cl;
      size_t off = (size_t)c * CH_STRIDE + (size_t)(f4 >> 1) * WIMG + (f4 & 1) * 4;
      float4 xv = *(const float4*)(xw + off);
      float4 ov;
      ov.x = g * o.x + xv.x; ov.y = g * o.y + xv.y;
      ov.z = g * o.z + xv.z; ov.w = g * o.w + xv.w;
      *(float4*)(ow + off) = ov;
    }
  }
}

extern "C" void kernel_launch(void* const* d_in, const int* in_sizes, int n_in,
                              void* d_out, int out_size, void* d_ws, size_t ws_size,
                              hipStream_t stream) {
  const float* x     = (const float*)d_in[0];
  const float* wq    = (const float*)d_in[1];
  const float* bq    = (const float*)d_in[2];
  const float* wk    = (const float*)d_in[3];
  const float* bk    = (const float*)d_in[4];
  const float* wv    = (const float*)d_in[5];
  const float* bv    = (const float*)d_in[6];
  const float* gamma = (const float*)d_in[7];
  float* out = (float*)d_out;
  __bf16* wsb = (__bf16*)d_ws;

  wprep_kernel<<<dim3(80), dim3(256), 0, stream>>>(wq, wk, wv, wsb);

  int B = in_sizes[0] / (CIN * CH_STRIDE);   // 4
  int nwin = B * 1024;
  win_attn_kernel<<<dim3(nwin), dim3(256), 0, stream>>>(
      x, wsb, bq, bk, bv, gamma, out, nwin);
}

// Round 5
// 272.428 us; speedup vs baseline: 1.2935x; 1.1032x over previous
//
#include <hip/hip_runtime.h>
#include <hip/hip_bf16.h>
#include <stdint.h>

// EfficientAttentionBlock: 8x8 window attention. B=4, C=256, H=W=256.
// 4096 windows; one 256-thread block per window; bf16 MFMA, fp32 accum.
// Round 5: true A/B fragment layout k = (j>>2)*16 + lq*4 + (j&3) (two K=16
// halves) -> swapped-MFMA C-regs feed next MFMA lane-locally. V stays in
// registers; P crosses waves via 8KB LDS (sigma-stored, XOR-swizzled, b128
// reads). O^T orientation -> float4 epilogue stores, residual from bf16 Xt.
// ws: bf16 weights: wq[32][256]@0, wk@8192, wv[256][256]@16384 (elems).

#define CIN    256
#define WIMG   256
#define CH_STRIDE 65536   // H*W

typedef __bf16 bf16x8 __attribute__((ext_vector_type(8)));
typedef float  f32x4  __attribute__((ext_vector_type(4)));

// LDS: Xt[64 px][256 ch] bf16 swizzled (32 KB); region1 (8 KB) = Qt+Kt, then P
#define XT_OFF 0
#define QT_OFF 32768
#define KT_OFF 36864
#define PT_OFF 32768
#define LDS_BYTES 40960   // 4 blocks/CU (160 KiB)

__device__ __forceinline__ int swz8(int p) { return (p ^ (p >> 3)) & 7; }

__device__ __forceinline__ uint32_t pack2(float lo, float hi) {
  union { __bf16 h[2]; uint32_t u; } un;
  un.h[0] = (__bf16)lo; un.h[1] = (__bf16)hi;
  return un.u;
}

union fragu { uint32_t u[4]; bf16x8 v; };

// ---------------- weight prep: fp32 -> bf16 row-major -----------------------
__global__ __launch_bounds__(256) void wprep_kernel(
    const float* __restrict__ wq, const float* __restrict__ wk,
    const float* __restrict__ wv, __bf16* __restrict__ out)
{
  int i = blockIdx.x * 256 + threadIdx.x;   // 20480 threads x 4 elems = 81920
  int off = i * 4;
  const float* src;
  if (off < 8192)       src = wq + off;
  else if (off < 16384) src = wk + (off - 8192);
  else                  src = wv + (off - 16384);
  float4 v = *(const float4*)src;
  __bf16 h[4] = {(__bf16)v.x, (__bf16)v.y, (__bf16)v.z, (__bf16)v.w};
  *(uint2*)(out + off) = *(const uint2*)h;
}

__global__ __launch_bounds__(256, 4) void win_attn_kernel(
    const float* __restrict__ x,  const __bf16* __restrict__ wsb,
    const float* __restrict__ bq, const float* __restrict__ bk,
    const float* __restrict__ bv, const float* __restrict__ gamma,
    float* __restrict__ out, int nwin)
{
  __shared__ __attribute__((aligned(16))) unsigned char lds[LDS_BYTES];

  // XCD-aware swizzle: contiguous chunk of windows per XCD. nwin % 8 == 0.
  int bid   = blockIdx.x;
  int chunk = nwin >> 3;
  int swz   = (bid & 7) * chunk + (bid >> 3);
  int b  = swz >> 10;
  int hw = (swz >> 5) & 31;
  int ww = swz & 31;
  size_t win_off = (size_t)b * (CIN * CH_STRIDE) + (size_t)hw * 8 * WIMG + (size_t)ww * 8;
  const float* xw = x + win_off;
  float* ow = out + win_off;

  int t = threadIdx.x;
  int w = t >> 6, l = t & 63, l16 = l & 15, lq = l >> 4;
  float g = gamma[0];

  // ---- preload bv for this lane's epilogue channels + Q/K weight frags ----
  float bvv[4];
  #pragma unroll
  for (int ci = 0; ci < 4; ++ci) bvv[ci] = bv[w * 64 + ci * 16 + l16];

  int qkrow = (w & 1) * 16;
  bf16x8 wqkf[8];
  {
    const __bf16* qrow = wsb + ((w < 2) ? 0 : 8192) + (qkrow + l16) * 256 + lq * 8;
    #pragma unroll
    for (int ks = 0; ks < 8; ++ks) wqkf[ks] = *(const bf16x8*)(qrow + ks * 32);
  }

  // ---------------- ph0: global x -> Xt (bf16, swizzled) --------------------
  #pragma unroll
  for (int it = 0; it < 8; ++it) {
    int id   = it * 256 + t;
    int half = id & 1;
    int i    = (id >> 1) & 7;
    int c2   = id >> 4;
    const float* r0 = xw + (size_t)(2 * c2) * CH_STRIDE + i * WIMG + half * 4;
    float4 va = *(const float4*)r0;
    float4 vb = *(const float4*)(r0 + CH_STRIDE);
    float ax[4] = {va.x, va.y, va.z, va.w};
    float bx[4] = {vb.x, vb.y, vb.z, vb.w};
    int blk = c2 >> 2;
    int sub = (c2 & 3) * 4;
    #pragma unroll
    for (int jj = 0; jj < 4; ++jj) {
      int p = i * 8 + half * 4 + jj;
      *(uint32_t*)(lds + XT_OFF + p * 512 + ((blk ^ swz8(p)) << 4) + sub) =
          pack2(ax[jj], bx[jj]);
    }
  }
  __syncthreads();   // B1: Xt visible

  // ---------------- ph1: Q/K projection (waves 0,1 = Q; 2,3 = K) ------------
  {
    f32x4 qacc[4] = {};
    #pragma unroll
    for (int ks = 0; ks < 8; ++ks) {
      bf16x8 xb[4];
      #pragma unroll
      for (int qi = 0; qi < 4; ++qi) {
        int p = qi * 16 + l16;
        xb[qi] = *(const bf16x8*)(lds + XT_OFF + p * 512 +
                                  (((ks * 4 + lq) ^ swz8(p)) << 4));
      }
      #pragma unroll
      for (int qi = 0; qi < 4; ++qi)
        qacc[qi] = __builtin_amdgcn_mfma_f32_16x16x32_bf16(wqkf[ks], xb[qi], qacc[qi], 0, 0, 0);
    }
    const float* bias = (w < 2) ? bq : bk;
    int lbase = (w < 2) ? QT_OFF : KT_OFF;
    #pragma unroll
    for (int r = 0; r < 4; ++r) {
      int c = qkrow + lq * 4 + r;
      float bb = bias[c];
      #pragma unroll
      for (int qi = 0; qi < 4; ++qi) {
        int p = qi * 16 + l16;
        *(__bf16*)(lds + lbase + p * 64 + (((c >> 3) ^ (p & 3)) << 4) + (c & 7) * 2) =
            (__bf16)(qacc[qi][r] + bb);
      }
    }
  }
  __syncthreads();   // B2: Qt/Kt visible

  // ---------------- ph2: S^T = mfma(K, Q), softmax in-register --------------
  // sacc[qi][r] = S[q = w*16+l16][kp = qi*16 + lq*4 + r]
  uint32_t dP[4][2];
  {
    int pq = w * 16 + l16;
    bf16x8 qa = *(const bf16x8*)(lds + QT_OFF + pq * 64 + ((lq ^ (pq & 3)) << 4));
    f32x4 sacc[4];
    #pragma unroll
    for (int qi = 0; qi < 4; ++qi) {
      int pk = qi * 16 + l16;
      bf16x8 kb = *(const bf16x8*)(lds + KT_OFF + pk * 64 + ((lq ^ (pk & 3)) << 4));
      f32x4 z = {0.f, 0.f, 0.f, 0.f};
      sacc[qi] = __builtin_amdgcn_mfma_f32_16x16x32_bf16(kb, qa, z, 0, 0, 0);
    }
    float e[4][4];
    float mx = -1e30f;
    #pragma unroll
    for (int qi = 0; qi < 4; ++qi)
      #pragma unroll
      for (int r = 0; r < 4; ++r) {
        float v = sacc[qi][r] * 0.125f;
        e[qi][r] = v;
        mx = fmaxf(mx, v);
      }
    mx = fmaxf(mx, __shfl_xor(mx, 16));
    mx = fmaxf(mx, __shfl_xor(mx, 32));
    float s = 0.f;
    #pragma unroll
    for (int qi = 0; qi < 4; ++qi)
      #pragma unroll
      for (int r = 0; r < 4; ++r) {
        e[qi][r] = __expf(e[qi][r] - mx);
        s += e[qi][r];
      }
    s += __shfl_xor(s, 16);
    s += __shfl_xor(s, 32);
    float inv = 1.0f / s;
    #pragma unroll
    for (int qi = 0; qi < 4; ++qi) {
      dP[qi][0] = pack2(e[qi][0] * inv, e[qi][1] * inv);
      dP[qi][1] = pack2(e[qi][2] * inv, e[qi][3] * inv);
    }
  }

  // ---------------- ph3: V^T = mfma(X, Wv) ----------------------------------
  // dV[pi][ci] dwords: V[c = w*64+ci*16+l16][vp = pi*16 + lq*4 + r], r=0..3
  uint32_t dV[4][4][2];
  {
    f32x4 vacc[4][4] = {};
    const __bf16* vrow = wsb + 16384 + (w * 64 + l16) * 256 + lq * 8;
    #pragma unroll
    for (int ks = 0; ks < 8; ++ks) {
      bf16x8 xb[4];
      #pragma unroll
      for (int pi = 0; pi < 4; ++pi) {
        int p = pi * 16 + l16;
        xb[pi] = *(const bf16x8*)(lds + XT_OFF + p * 512 +
                                  (((ks * 4 + lq) ^ swz8(p)) << 4));
      }
      #pragma unroll
      for (int ci = 0; ci < 4; ++ci) {
        bf16x8 wvf = *(const bf16x8*)(vrow + ci * 16 * 256 + ks * 32);
        #pragma unroll
        for (int pi = 0; pi < 4; ++pi)
          vacc[pi][ci] = __builtin_amdgcn_mfma_f32_16x16x32_bf16(xb[pi], wvf, vacc[pi][ci], 0, 0, 0);
      }
    }
    #pragma unroll
    for (int pi = 0; pi < 4; ++pi)
      #pragma unroll
      for (int ci = 0; ci < 4; ++ci) {
        dV[pi][ci][0] = pack2(vacc[pi][ci][0], vacc[pi][ci][1]);
        dV[pi][ci][1] = pack2(vacc[pi][ci][2], vacc[pi][ci][3]);
      }
  }
  __syncthreads();   // B3: all Qt/Kt reads complete -> region1 reusable

  // ---------------- P -> LDS (sigma-stored, XOR-swizzled) -------------------
  // storage idx(kp): kp = ks*32 + half*16 + lq*4 + r  ->  ks*32 + lq*8 + half*4 + r
  {
    int q = w * 16 + l16;
    int qm = q & 7;
    #pragma unroll
    for (int qi = 0; qi < 4; ++qi) {
      int blk = (((qi >> 1) * 4) + lq) ^ qm;
      uint2 val; val.x = dP[qi][0]; val.y = dP[qi][1];
      *(uint2*)(lds + PT_OFF + q * 128 + blk * 16 + (qi & 1) * 8) = val;
    }
  }
  __syncthreads();   // B4: P visible

  // ---------------- ph4: O^T = mfma(P, V) -----------------------------------
  // oacc[ci][bj][r] = O[c = w*64+ci*16+l16][p = bj*16 + lq*4 + r]
  f32x4 oacc[4][4] = {};
  #pragma unroll
  for (int ks = 0; ks < 2; ++ks) {
    bf16x8 Pf[4];
    #pragma unroll
    for (int bj = 0; bj < 4; ++bj) {
      int q = bj * 16 + l16;
      int blk = (ks * 4 + lq) ^ (q & 7);
      Pf[bj] = *(const bf16x8*)(lds + PT_OFF + q * 128 + blk * 16);
    }
    #pragma unroll
    for (int ci = 0; ci < 4; ++ci) {
      fragu Vf;
      Vf.u[0] = dV[2 * ks][ci][0];
      Vf.u[1] = dV[2 * ks][ci][1];
      Vf.u[2] = dV[2 * ks + 1][ci][0];
      Vf.u[3] = dV[2 * ks + 1][ci][1];
      #pragma unroll
      for (int bj = 0; bj < 4; ++bj)
        oacc[ci][bj] = __builtin_amdgcn_mfma_f32_16x16x32_bf16(Pf[bj], Vf.v, oacc[ci][bj], 0, 0, 0);
    }
  }

  // ---------------- epilogue: out = g*(O + bv) + x, float4 stores -----------
  #pragma unroll
  for (int ci = 0; ci < 4; ++ci) {
    int c = w * 64 + ci * 16 + l16;
    size_t cbase = (size_t)c * CH_STRIDE;
    float bvc = bvv[ci];
    int chi = c >> 3, clo = (c & 7) * 2;
    #pragma unroll
    for (int bj = 0; bj < 4; ++bj) {
      int p0 = bj * 16 + lq * 4;
      float xr[4];
      #pragma unroll
      for (int r = 0; r < 4; ++r) {
        int p = p0 + r;
        xr[r] = (float)(*(const __bf16*)(lds + XT_OFF + p * 512 +
                                         ((chi ^ swz8(p)) << 4) + clo));
      }
      float4 o;
      o.x = g * (oacc[ci][bj][0] + bvc) + xr[0];
      o.y = g * (oacc[ci][bj][1] + bvc) + xr[1];
      o.z = g * (oacc[ci][bj][2] + bvc) + xr[2];
      o.w = g * (oacc[ci][bj][3] + bvc) + xr[3];
      *(float4*)(ow + cbase + (size_t)(p0 >> 3) * WIMG + (p0 & 7)) = o;
    }
  }
}

extern "C" void kernel_launch(void* const* d_in, const int* in_sizes, int n_in,
                              void* d_out, int out_size, void* d_ws, size_t ws_size,
                              hipStream_t stream) {
  const float* x     = (const float*)d_in[0];
  const float* wq    = (const float*)d_in[1];
  const float* bq    = (const float*)d_in[2];
  const float* wk    = (const float*)d_in[3];
  const float* bk    = (const float*)d_in[4];
  const float* wv    = (const float*)d_in[5];
  const float* bv    = (const float*)d_in[6];
  const float* gamma = (const float*)d_in[7];
  float* out = (float*)d_out;
  __bf16* wsb = (__bf16*)d_ws;

  wprep_kernel<<<dim3(80), dim3(256), 0, stream>>>(wq, wk, wv, wsb);

  int B = in_sizes[0] / (CIN * CH_STRIDE);   // 4
  int nwin = B * 1024;
  win_attn_kernel<<<dim3(nwin), dim3(256), 0, stream>>>(
      x, wsb, bq, bk, bv, gamma, out, nwin);
}